// Round 3
// baseline (198.253 us; speedup 1.0000x reference)
//
#include <hip/hip_runtime.h>
#include <stdint.h>

#define BDIM 8192
#define DDIM 128
#define NCHUNK 32
#define ROWS_PER_BLOCK 256
#define COLS_PER_BLOCK (2 * BDIM / NCHUNK)  // 512

constexpr float TEMP_ = 0.5f;
constexpr float LOG2E = 1.4426950408889634f;
constexpr float LN2F = 0.6931471805599453f;
constexpr float QSCALE = LOG2E / TEMP_;  // 2.8853901...

typedef __attribute__((ext_vector_type(8))) short bf16x8;
typedef __attribute__((ext_vector_type(4))) float f32x4;

__device__ inline float fexp2(float x) {
#if __has_builtin(__builtin_amdgcn_exp2f)
  return __builtin_amdgcn_exp2f(x);
#else
  return exp2f(x);
#endif
}

__device__ inline float flog2(float x) {
#if __has_builtin(__builtin_amdgcn_logf)
  return __builtin_amdgcn_logf(x);
#else
  return log2f(x);
#endif
}

// float -> bf16 round-to-nearest-even (inputs finite)
__device__ inline unsigned short f2bf(float f) {
  unsigned int u = __float_as_uint(f);
  u += 0x7FFFu + ((u >> 16) & 1u);
  return (unsigned short)(u >> 16);
}

// ---------------------------------------------------------------------------
// Kernel 1: normalize rows of zis/zjs, write bf16 copies + fp32 pos logit.
//  qs[i][d]   = bf16( zi_n[i][d] * QSCALE )   (Q operand, log2e/TEMP folded in)
//  kc[i][d]   = bf16( zj_n[i][d] )            (cols 0..B-1  = s_ij)
//  kc[B+i][d] = bf16( zi_n[i][d] )            (cols B..2B-1 = s_ik)
//  post[i]    = dot(zi_n, zj_n) / TEMP        (fp32-accurate pos logit)
// One wave per row; 2 floats per lane.
// ---------------------------------------------------------------------------
__global__ __launch_bounds__(256) void nk(const float* __restrict__ zis,
                                          const float* __restrict__ zjs,
                                          unsigned short* __restrict__ qs,
                                          unsigned short* __restrict__ kc,
                                          float* __restrict__ post) {
  const int wid = threadIdx.x >> 6;
  const int lane = threadIdx.x & 63;
  const int row = blockIdx.x * 4 + wid;
  const float2 zi = *(const float2*)(zis + (size_t)row * DDIM + lane * 2);
  const float2 zj = *(const float2*)(zjs + (size_t)row * DDIM + lane * 2);
  float ssi = zi.x * zi.x + zi.y * zi.y;
  float ssj = zj.x * zj.x + zj.y * zj.y;
  float dot = zi.x * zj.x + zi.y * zj.y;
#pragma unroll
  for (int off = 32; off >= 1; off >>= 1) {
    ssi += __shfl_xor(ssi, off);
    ssj += __shfl_xor(ssj, off);
    dot += __shfl_xor(dot, off);
  }
  const float invi = 1.0f / fmaxf(sqrtf(ssi), 1e-8f);
  const float invj = 1.0f / fmaxf(sqrtf(ssj), 1e-8f);
  const float tpos = dot * invi * invj * (1.0f / TEMP_);

  const float qi0 = zi.x * invi, qi1 = zi.y * invi;
  const float qj0 = zj.x * invj, qj1 = zj.y * invj;

  ushort2 w;
  w.x = f2bf(qi0 * QSCALE); w.y = f2bf(qi1 * QSCALE);
  *(ushort2*)(qs + (size_t)row * DDIM + lane * 2) = w;
  w.x = f2bf(qj0); w.y = f2bf(qj1);
  *(ushort2*)(kc + (size_t)row * DDIM + lane * 2) = w;
  w.x = f2bf(qi0); w.y = f2bf(qi1);
  *(ushort2*)(kc + (size_t)(BDIM + row) * DDIM + lane * 2) = w;

  if (lane == 0) post[row] = tpos;
}

// ---------------------------------------------------------------------------
// Kernel 2: fused similarity GEMM + streaming sum of exp2.
// Swapped MFMA (A = kc cols, B = qs rows): lane's 4 C-regs = 4 consecutive
// similarity-cols of ONE q-row (C layout: qrow=lane&15, col=(lane>>4)*4+r).
// Each wave owns 32 q-rows (two 16-row fragments sharing each A-frag load).
// Columns with id == row id are excluded (uniform over both halves; with
// unique ids that's exactly the diagonal); fp32 pos re-added in kernel 3.
// Per-lane running fp32 sums; partials -> su[] via atomicAdd.
// ---------------------------------------------------------------------------
__global__ __launch_bounds__(512) void mk(const unsigned short* __restrict__ qs,
                                          const unsigned short* __restrict__ kc,
                                          const int* __restrict__ ids,
                                          float* __restrict__ su) {
  const int wid = threadIdx.x >> 6;
  const int lane = threadIdx.x & 63;
  const int rb = blockIdx.x & 31;   // 32 row blocks (x 256 rows)
  const int cb = blockIdx.x >> 5;   // NCHUNK col chunks
  const int q0 = rb * ROWS_PER_BLOCK + wid * 32;
  const int qr = lane & 15;
  const int kg = lane >> 4;

  // Q fragments (B operand): lane holds q-row (q0+qr)/(q0+16+qr), k=kk*32+kg*8+j
  bf16x8 qA[4], qB[4];
  const unsigned short* qbaseA = qs + (size_t)(q0 + qr) * DDIM + kg * 8;
  const unsigned short* qbaseB = qbaseA + 16 * DDIM;
#pragma unroll
  for (int kk = 0; kk < 4; kk++) {
    qA[kk] = *(const bf16x8*)(qbaseA + kk * 32);
    qB[kk] = *(const bf16x8*)(qbaseB + kk * 32);
  }
  const int idA = ids[q0 + qr];
  const int idB = ids[q0 + 16 + qr];

  f32x4 accA = {0.f, 0.f, 0.f, 0.f};   // 8 independent FP-add chains
  f32x4 accB = {0.f, 0.f, 0.f, 0.f};
  const int c0 = cb * COLS_PER_BLOCK;
  const unsigned short* kp = kc + (size_t)(c0 + qr) * DDIM + kg * 8;

#pragma unroll 2
  for (int t = 0; t < COLS_PER_BLOCK / 16; t++) {
    // ids for this lane's 4 output cols (consecutive) — issue load early
    const int colbase = c0 + t * 16 + kg * 4;
    const int4 idv = *(const int4*)(ids + (colbase & (BDIM - 1)));

    f32x4 aA = {0.f, 0.f, 0.f, 0.f};
    f32x4 aB = {0.f, 0.f, 0.f, 0.f};
#pragma unroll
    for (int kk = 0; kk < 4; kk++) {
      const bf16x8 af = *(const bf16x8*)(kp + kk * 32);  // A: col c0+t*16+qr
      aA = __builtin_amdgcn_mfma_f32_16x16x32_bf16(af, qA[kk], aA, 0, 0, 0);
      aB = __builtin_amdgcn_mfma_f32_16x16x32_bf16(af, qB[kk], aB, 0, 0, 0);
    }
#pragma unroll
    for (int r = 0; r < 4; r++) {
      const int idc = (&idv.x)[r];
      accA[r] += (idc == idA) ? 0.0f : fexp2(aA[r]);
      accB[r] += (idc == idB) ? 0.0f : fexp2(aB[r]);
    }
    kp += 16 * DDIM;
    if ((t & 3) == 3) __syncthreads();  // bound wave skew for L1 K-tile reuse
  }

  float sA = accA[0] + accA[1] + accA[2] + accA[3];
  float sB = accB[0] + accB[1] + accB[2] + accB[3];
  // lanes l, l^16, l^32, l^48 hold the same q-row -> 2-step butterfly
  sA += __shfl_xor(sA, 16); sA += __shfl_xor(sA, 32);
  sB += __shfl_xor(sB, 16); sB += __shfl_xor(sB, 32);
  if (lane < 16) {
    atomicAdd(&su[q0 + lane], sA);
    atomicAdd(&su[q0 + 16 + lane], sB);
  }
}

// ---------------------------------------------------------------------------
// Kernel 3: per-row  lse = ln2*log2(su + exp2(pos*log2e));  loss += lse - pos.
// ---------------------------------------------------------------------------
__global__ __launch_bounds__(256) void fk(const float* __restrict__ su,
                                          const float* __restrict__ post,
                                          float* __restrict__ out) {
  const int i = blockIdx.x * 256 + threadIdx.x;
  const float tp = post[i];
  const float v = su[i] + fexp2(tp * LOG2E);
  float c = (LN2F * flog2(v) - tp) * (1.0f / (2.0f * BDIM));
#pragma unroll
  for (int off = 32; off >= 1; off >>= 1) c += __shfl_xor(c, off);
  if ((threadIdx.x & 63) == 0) atomicAdd(out, c);
}

// ---------------------------------------------------------------------------
extern "C" void kernel_launch(void* const* d_in, const int* in_sizes, int n_in,
                              void* d_out, int out_size, void* d_ws, size_t ws_size,
                              hipStream_t stream) {
  const float* zis = (const float*)d_in[0];
  const float* zjs = (const float*)d_in[1];
  const int* ids = (const int*)d_in[2];

  char* ws = (char*)d_ws;
  unsigned short* qs = (unsigned short*)ws;                              // 2 MiB
  unsigned short* kc = (unsigned short*)(ws + (size_t)2 * 1024 * 1024);  // 4 MiB
  float* post = (float*)(ws + (size_t)6 * 1024 * 1024);                  // 32 KiB
  float* su = (float*)(ws + (size_t)6 * 1024 * 1024 + 32768);            // 32 KiB

  hipMemsetAsync(d_out, 0, sizeof(float), stream);
  hipMemsetAsync(su, 0, BDIM * sizeof(float), stream);

  nk<<<BDIM / 4, 256, 0, stream>>>(zis, zjs, qs, kc, post);
  mk<<<32 * NCHUNK, 512, 0, stream>>>(qs, kc, ids, su);
  fk<<<BDIM / 256, 256, 0, stream>>>(su, post, (float*)d_out);
}

// Round 12
// 115.798 us; speedup vs baseline: 1.7121x; 1.7121x over previous
//
#include <hip/hip_runtime.h>
#include <stdint.h>

#define BDIM 8192
#define DDIM 128
#define NCHUNK 16
#define ROWS_PER_BLOCK 256
#define COLS_PER_BLOCK (2 * BDIM / NCHUNK)  // 1024
#define TCOLS 32                            // cols per LDS tile
#define NT (COLS_PER_BLOCK / TCOLS)         // 32 tiles

#if __has_builtin(__builtin_amdgcn_global_load_lds)
#define HAS_GLOAD_LDS 1
#else
#define HAS_GLOAD_LDS 0
#endif

constexpr float TEMP_ = 0.5f;
constexpr float LOG2E = 1.4426950408889634f;
constexpr float LN2F = 0.6931471805599453f;
constexpr float QSCALE = LOG2E / TEMP_;  // 2.8853901...

typedef __attribute__((ext_vector_type(8))) short bf16x8;
typedef __attribute__((ext_vector_type(4))) float f32x4;

__device__ inline float fexp2(float x) {
#if __has_builtin(__builtin_amdgcn_exp2f)
  return __builtin_amdgcn_exp2f(x);
#else
  return exp2f(x);
#endif
}

__device__ inline float flog2(float x) {
#if __has_builtin(__builtin_amdgcn_logf)
  return __builtin_amdgcn_logf(x);
#else
  return log2f(x);
#endif
}

#if HAS_GLOAD_LDS
// global_load_lds with explicit address-space casts (builtin params are
// AS(1)/AS(3)-qualified; generic pointers don't implicitly convert).
__device__ inline void gload_lds16(const void* g, void* l) {
  __builtin_amdgcn_global_load_lds(
      (const __attribute__((address_space(1))) void*)g,
      (__attribute__((address_space(3))) void*)l, 16, 0, 0);
}
#endif

// float -> bf16 round-to-nearest-even (inputs finite)
__device__ inline unsigned short f2bf(float f) {
  unsigned int u = __float_as_uint(f);
  u += 0x7FFFu + ((u >> 16) & 1u);
  return (unsigned short)(u >> 16);
}

// ---------------------------------------------------------------------------
// Kernel 1: normalize rows of zis/zjs, write bf16 copies + fp32 pos logit.
//  qs[i][d]   = bf16( zi_n[i][d] * QSCALE )   (Q operand, log2e/TEMP folded in)
//  kc[i][d]   = bf16( zj_n[i][d] )            (cols 0..B-1  = s_ij)
//  kc[B+i][d] = bf16( zi_n[i][d] )            (cols B..2B-1 = s_ik)
//  post[i]    = dot(zi_n, zj_n) / TEMP        (fp32-accurate pos logit)
// ---------------------------------------------------------------------------
__global__ __launch_bounds__(256) void nk(const float* __restrict__ zis,
                                          const float* __restrict__ zjs,
                                          unsigned short* __restrict__ qs,
                                          unsigned short* __restrict__ kc,
                                          float* __restrict__ post) {
  const int wid = threadIdx.x >> 6;
  const int lane = threadIdx.x & 63;
  const int row = blockIdx.x * 4 + wid;
  const float2 zi = *(const float2*)(zis + (size_t)row * DDIM + lane * 2);
  const float2 zj = *(const float2*)(zjs + (size_t)row * DDIM + lane * 2);
  float ssi = zi.x * zi.x + zi.y * zi.y;
  float ssj = zj.x * zj.x + zj.y * zj.y;
  float dot = zi.x * zj.x + zi.y * zj.y;
#pragma unroll
  for (int off = 32; off >= 1; off >>= 1) {
    ssi += __shfl_xor(ssi, off);
    ssj += __shfl_xor(ssj, off);
    dot += __shfl_xor(dot, off);
  }
  const float invi = 1.0f / fmaxf(sqrtf(ssi), 1e-8f);
  const float invj = 1.0f / fmaxf(sqrtf(ssj), 1e-8f);
  const float tpos = dot * invi * invj * (1.0f / TEMP_);

  const float qi0 = zi.x * invi, qi1 = zi.y * invi;
  const float qj0 = zj.x * invj, qj1 = zj.y * invj;

  ushort2 w;
  w.x = f2bf(qi0 * QSCALE); w.y = f2bf(qi1 * QSCALE);
  *(ushort2*)(qs + (size_t)row * DDIM + lane * 2) = w;
  w.x = f2bf(qj0); w.y = f2bf(qj1);
  *(ushort2*)(kc + (size_t)row * DDIM + lane * 2) = w;
  w.x = f2bf(qi0); w.y = f2bf(qi1);
  *(ushort2*)(kc + (size_t)(BDIM + row) * DDIM + lane * 2) = w;

  if (lane == 0) post[row] = tpos;
}

// ---------------------------------------------------------------------------
// Kernel 2: fused similarity GEMM + streaming sum of exp2 — LDS-staged.
// Per block: 256 q-rows (8 waves x 32), 1024 cols in 32-col double-buffered
// LDS tiles. Staging: global_load_lds(16B) when available, else reg-staged
// (load early / ds_write late, same byte placement). LDS linear; bank-conflict
// fix is the both-sides involution (rule #21): source pre-swizzled with
//   off ^ ((col&7)<<4),  same XOR applied on ds_read addresses.
// Swapped MFMA (A = kc cols, B = qs rows): C layout qrow=lane&15,
// col = cg*16 + (lane>>4)*4 + r. Columns with id == row id excluded;
// fp32 pos re-added in kernel 3. Partials -> su[] via atomicAdd.
// ---------------------------------------------------------------------------
__global__ __launch_bounds__(512, 4) void mk(const unsigned short* __restrict__ qs,
                                             const unsigned short* __restrict__ kc,
                                             const int* __restrict__ ids,
                                             float* __restrict__ su) {
  __shared__ char lds[2 * 8192 + COLS_PER_BLOCK * 4];
  int* ids_l = (int*)(lds + 16384);

  const int tid = threadIdx.x;
  const int wid = tid >> 6;
  const int lane = tid & 63;
  const int qr = lane & 15;
  const int kg = lane >> 4;

  // XCD-chunked swizzle: 512 blocks -> 64 consecutive per XCD; blocks on one
  // XCD share 2 col-chunks (512 KB of kc L2-resident) + all of qs.
  const int swz = (blockIdx.x & 7) * 64 + (blockIdx.x >> 3);
  const int rb = swz & 31;   // 32 row blocks
  const int cb = swz >> 5;   // 16 col chunks
  const int q0 = rb * ROWS_PER_BLOCK + wid * 32;
  const int c0 = cb * COLS_PER_BLOCK;

  // stage this block's col ids into LDS (2 per thread)
#pragma unroll
  for (int c = tid; c < COLS_PER_BLOCK; c += 512)
    ids_l[c] = ids[(c0 + c) & (BDIM - 1)];

  // Q fragments (B operand): lane holds q-row (q0+qr)/(q0+16+qr), k=kk*32+kg*8+j
  bf16x8 qA[4], qB[4];
  const unsigned short* qbaseA = qs + (size_t)(q0 + qr) * DDIM + kg * 8;
  const unsigned short* qbaseB = qbaseA + 16 * DDIM;
#pragma unroll
  for (int kk = 0; kk < 4; kk++) {
    qA[kk] = *(const bf16x8*)(qbaseA + kk * 32);
    qB[kk] = *(const bf16x8*)(qbaseB + kk * 32);
  }
  const int idA = ids[q0 + qr];
  const int idB = ids[q0 + 16 + qr];

  // staging: thread tid covers LDS bytes tid*16..+15 of an 8 KB (32x128 bf16)
  // tile; col = tid>>4, slot = tid&15; global source pre-swizzled.
  const int scol = tid >> 4;
  const int sslot = tid & 15;
  const char* kcb = (const char*)kc;
  const int gsoff = scol * 256 + ((sslot * 16) ^ ((scol & 7) << 4));
#if HAS_GLOAD_LDS
  char* ldst = lds + wid * 1024;  // wave-uniform dest base (+ lane*16 implicit)
#endif

  int cur = 0;
#if HAS_GLOAD_LDS
  gload_lds16(kcb + (size_t)(c0) * 256 + gsoff, ldst);
#else
  *(int4*)(lds + tid * 16) = *(const int4*)(kcb + (size_t)(c0) * 256 + gsoff);
#endif
  __syncthreads();  // tile 0 and ids_l visible (vmcnt+lgkm drained)

  f32x4 acc[2][2] = {{{0.f, 0.f, 0.f, 0.f}, {0.f, 0.f, 0.f, 0.f}},
                     {{0.f, 0.f, 0.f, 0.f}, {0.f, 0.f, 0.f, 0.f}}};

  for (int t = 0; t < NT; ++t) {
#if !HAS_GLOAD_LDS
    int4 pf;
#endif
    if (t + 1 < NT) {  // prefetch next tile into the other buffer
      const char* gp = kcb + (size_t)(c0 + (t + 1) * TCOLS) * 256 + gsoff;
#if HAS_GLOAD_LDS
      gload_lds16(gp, ldst + (cur ^ 1) * 8192);
#else
      pf = *(const int4*)gp;  // issue early; ds_write after compute
#endif
    }

    const char* kb = lds + cur * 8192;
#pragma unroll
    for (int cg = 0; cg < 2; ++cg) {
      const int col = cg * 16 + qr;
      const char* abase = kb + col * 256;
      f32x4 aT0 = {0.f, 0.f, 0.f, 0.f};
      f32x4 aT1 = {0.f, 0.f, 0.f, 0.f};
#pragma unroll
      for (int kk = 0; kk < 4; ++kk) {
        const int off = (kk * 64 + kg * 16) ^ ((qr & 7) << 4);  // read-side XOR
        const bf16x8 af = *(const bf16x8*)(abase + off);
        aT0 = __builtin_amdgcn_mfma_f32_16x16x32_bf16(af, qA[kk], aT0, 0, 0, 0);
        aT1 = __builtin_amdgcn_mfma_f32_16x16x32_bf16(af, qB[kk], aT1, 0, 0, 0);
      }
      const int4 idv = *(const int4*)&ids_l[t * TCOLS + cg * 16 + kg * 4];
#pragma unroll
      for (int r = 0; r < 4; ++r) {
        const int idc = (&idv.x)[r];
        acc[cg][0][r] += (idc == idA) ? 0.0f : fexp2(aT0[r]);
        acc[cg][1][r] += (idc == idB) ? 0.0f : fexp2(aT1[r]);
      }
    }
#if !HAS_GLOAD_LDS
    if (t + 1 < NT) *(int4*)(lds + (cur ^ 1) * 8192 + tid * 16) = pf;
#endif
    __syncthreads();  // next tile staged + buffer reuse safe
    cur ^= 1;
  }

  float sA = acc[0][0][0] + acc[0][0][1] + acc[0][0][2] + acc[0][0][3] +
             acc[1][0][0] + acc[1][0][1] + acc[1][0][2] + acc[1][0][3];
  float sB = acc[0][1][0] + acc[0][1][1] + acc[0][1][2] + acc[0][1][3] +
             acc[1][1][0] + acc[1][1][1] + acc[1][1][2] + acc[1][1][3];
  // lanes l, l^16, l^32, l^48 hold the same q-row -> 2-step butterfly
  sA += __shfl_xor(sA, 16); sA += __shfl_xor(sA, 32);
  sB += __shfl_xor(sB, 16); sB += __shfl_xor(sB, 32);
  if (lane < 16) {
    atomicAdd(&su[q0 + lane], sA);
    atomicAdd(&su[q0 + 16 + lane], sB);
  }
}

// ---------------------------------------------------------------------------
// Kernel 3: per-row  lse = ln2*log2(su + exp2(pos*log2e));  loss += lse - pos.
// ---------------------------------------------------------------------------
__global__ __launch_bounds__(256) void fk(const float* __restrict__ su,
                                          const float* __restrict__ post,
                                          float* __restrict__ out) {
  const int i = blockIdx.x * 256 + threadIdx.x;
  const float tp = post[i];
  const float v = su[i] + fexp2(tp * LOG2E);
  float c = (LN2F * flog2(v) - tp) * (1.0f / (2.0f * BDIM));
#pragma unroll
  for (int off = 32; off >= 1; off >>= 1) c += __shfl_xor(c, off);
  if ((threadIdx.x & 63) == 0) atomicAdd(out, c);
}

// ---------------------------------------------------------------------------
extern "C" void kernel_launch(void* const* d_in, const int* in_sizes, int n_in,
                              void* d_out, int out_size, void* d_ws, size_t ws_size,
                              hipStream_t stream) {
  const float* zis = (const float*)d_in[0];
  const float* zjs = (const float*)d_in[1];
  const int* ids = (const int*)d_in[2];

  char* ws = (char*)d_ws;
  unsigned short* qs = (unsigned short*)ws;                              // 2 MiB
  unsigned short* kc = (unsigned short*)(ws + (size_t)2 * 1024 * 1024);  // 4 MiB
  float* post = (float*)(ws + (size_t)6 * 1024 * 1024);                  // 32 KiB
  float* su = (float*)(ws + (size_t)6 * 1024 * 1024 + 32768);            // 32 KiB

  hipMemsetAsync(d_out, 0, sizeof(float), stream);
  hipMemsetAsync(su, 0, BDIM * sizeof(float), stream);

  nk<<<BDIM / 4, 256, 0, stream>>>(zis, zjs, qs, kc, post);
  mk<<<32 * NCHUNK, 512, 0, stream>>>(qs, kc, ids, su);
  fk<<<BDIM / 256, 256, 0, stream>>>(su, post, (float*)d_out);
}